// Round 15
// baseline (242.190 us; speedup 1.0000x reference)
//
#include <hip/hip_runtime.h>
#include <hip/hip_bf16.h>

// EncoderLayer B=4,S=2048,D=512,H=8,HD=64,E=4. Inputs fp32, OUTPUT fp32.
// R27: R22 base (best: 239.0) + flash rsum-via-MFMA:
//  - row-sum of P computed by 4 extra mfma32x16(paw[w], ONES, racc) per
//    iter (matrix pipe at 27% has capacity) instead of 32 VALU adds + final
//    shfl_xor + 16 epilogue shuffles. A-frag k-map (k=hi*8+j <-> s=w0+hi*8+j)
//    makes the MFMA sum BOTH hi halves internally; racc[r] is directly the
//    denominator for row qloc(r,hi) (same C/D row map as oacc).
//  - QKV back to R22 2-buffer (R26's 3-ring at iso-occupancy was neutral).
//  - Everything else identical to R22: gemm256v2 FFN1, TN=64 3-ring Wo/FFN2,
//    prep, XCD chunked swizzle, Q-scale fold, max-free exp2 softmax.

typedef __bf16 bf16;
typedef __attribute__((ext_vector_type(8))) __bf16 bf16x8;
typedef __attribute__((ext_vector_type(4))) __bf16 bf16x4;
typedef __attribute__((ext_vector_type(4))) float f32x4;
typedef __attribute__((ext_vector_type(16))) float f32x16;
typedef __attribute__((ext_vector_type(2))) unsigned int u32x2;
typedef __attribute__((ext_vector_type(4))) unsigned int u32x4;

#define LOG2E 1.4426950408889634f
#define SCORE_SCALE 0.044194173824159216f /* 512^-0.5 (D^-0.25 on q AND k) */
#define SCALE_L2E (SCORE_SCALE * LOG2E)   /* folded into stored Q */

#if __has_builtin(__builtin_amdgcn_exp2f)
#define EXP2(x) __builtin_amdgcn_exp2f(x)
#else
#define EXP2(x) exp2f(x)
#endif

__device__ __forceinline__ void gl_lds16(const bf16* g, bf16* l) {
  __builtin_amdgcn_global_load_lds(
      (const __attribute__((address_space(1))) unsigned int*)g,
      (__attribute__((address_space(3))) unsigned int*)l, 16, 0, 0);
}

template <int N>
__device__ __forceinline__ void wait_vm_barrier() {
  if constexpr (N == 0)
    asm volatile("s_waitcnt vmcnt(0)\ns_barrier" ::: "memory");
  else if constexpr (N == 3)
    asm volatile("s_waitcnt vmcnt(3)\ns_barrier" ::: "memory");
  else if constexpr (N == 4)
    asm volatile("s_waitcnt vmcnt(4)\ns_barrier" ::: "memory");
  else if constexpr (N == 8)
    asm volatile("s_waitcnt vmcnt(8)\ns_barrier" ::: "memory");
}

__device__ __forceinline__ float gelu_tanh(float x) {
  float u = 0.7978845608028654f * (x + 0.044715f * x * x * x);
  float e = EXP2(u * (2.0f * LOG2E));   // e^(2u)
  float th = 1.0f - 2.0f / (e + 1.0f);  // tanh(u), saturates at +-1
  return 0.5f * x * (1.0f + th);
}

__device__ __forceinline__ f32x4 mfma_bf16(bf16x8 a, bf16x8 b, f32x4 c) {
  return __builtin_amdgcn_mfma_f32_16x16x32_bf16(a, b, c, 0, 0, 0);
}
__device__ __forceinline__ f32x16 mfma32x16(bf16x8 a, bf16x8 b, f32x16 c) {
  return __builtin_amdgcn_mfma_f32_32x32x16_bf16(a, b, c, 0, 0, 0);
}

// v_permlane32_swap_b32: vdst.hi32lanes <-> src.lo32lanes (writes BOTH).
__device__ __forceinline__ void plswap(unsigned int& a, unsigned int& b) {
  asm volatile("v_permlane32_swap_b32 %0, %1" : "+v"(a), "+v"(b));
}

// Chunked bijective XCD remap (requires nwg%8==0).
__device__ __forceinline__ void xcd_remap(int& bx, int& by) {
  const int gx = gridDim.x;
  const int nwg = gx * gridDim.y;
  const int lin = blockIdx.y * gx + blockIdx.x;
  const int id = (lin & 7) * (nwg >> 3) + (lin >> 3);
  bx = id % gx;
  by = id / gx;
}

// ---------------- GEMM: C[M,N] = A[M,K] @ Bt[N,K]^T ------------------------
// TN=128: 2-buffer __syncthreads (R11/R22). TN=64: 3-ring counted vmcnt(3).
// MODE 0: Q panel (n0<512) scaled by SCALE_L2E; V panel (n0>=1024) written
// transposed into vt.
template <int MODE, typename OutT, int TN>
__global__ __launch_bounds__(256, 2) void gemm_bt(
    const bf16* __restrict__ A, const bf16* __restrict__ Bt,
    OutT* __restrict__ C, const float* __restrict__ bias,
    const float* __restrict__ resf, const bf16* __restrict__ resb,
    bf16* __restrict__ vt, int M, int N, int K) {
  constexpr int MI = (TN == 128) ? 4 : 2;
  constexpr int NBUF = (TN == 128) ? 2 : 3;
  __shared__ __align__(16) bf16 sA[NBUF][128 * 32];
  __shared__ __align__(16) bf16 sB[NBUF][TN * 32];
  const int tid = threadIdx.x;
  const int lane = tid & 63;
  const int quad = lane >> 4, lc = lane & 15;
  const int wave = tid >> 6;
  const int wr = (TN == 128) ? (wave >> 1) : wave;
  const int wc = (TN == 128) ? (wave & 1) : 0;
  int bxs, bys;
  xcd_remap(bxs, bys);
  const int m0 = bys * 128, n0 = bxs * TN;

  const int srow = tid >> 2;
  const int kc = (tid & 3) * 8;
  const bf16* Ag1 = A + (size_t)(m0 + srow) * K + kc;
  const bf16* Ag2 = A + (size_t)(m0 + 64 + srow) * K + kc;
  const bf16* Bg1 = Bt + (size_t)(n0 + srow) * K + kc;
  const bf16* Bg2 = Bt + (size_t)(n0 + 64 + srow) * K + kc;
  const int o1 = tid * 8, o2 = (tid + 256) * 8;

  f32x4 acc[MI][4];
#pragma unroll
  for (int mi = 0; mi < MI; ++mi)
#pragma unroll
    for (int ni = 0; ni < 4; ++ni) acc[mi][ni] = (f32x4){0.f, 0.f, 0.f, 0.f};

  const int kIters = K >> 5;

  if constexpr (TN == 128) {
    gl_lds16(Ag1, sA[0] + o1);
    gl_lds16(Ag2, sA[0] + o2);
    gl_lds16(Bg1, sB[0] + o1);
    gl_lds16(Bg2, sB[0] + o2);
    Ag1 += 32; Ag2 += 32; Bg1 += 32; Bg2 += 32;

    for (int kt = 0; kt < kIters; ++kt) {
      __syncthreads();
      const bf16* cA = sA[kt & 1];
      const bf16* cB = sB[kt & 1];
      if (kt + 1 < kIters) {
        bf16* nA = sA[(kt + 1) & 1];
        bf16* nB = sB[(kt + 1) & 1];
        gl_lds16(Ag1, nA + o1);
        gl_lds16(Ag2, nA + o2);
        gl_lds16(Bg1, nB + o1);
        gl_lds16(Bg2, nB + o2);
        Ag1 += 32; Ag2 += 32; Bg1 += 32; Bg2 += 32;
      }
      bf16x8 af[MI], bfm[4];
#pragma unroll
      for (int i = 0; i < MI; ++i)
        af[i] = *(const bf16x8*)(cA +
                                 ((wr * 64 + i * 16 + lc) * 32 + quad * 8));
#pragma unroll
      for (int i = 0; i < 4; ++i)
        bfm[i] =
            *(const bf16x8*)(cB + ((wc * 64 + i * 16 + lc) * 32 + quad * 8));
#pragma unroll
      for (int mi = 0; mi < MI; ++mi)
#pragma unroll
        for (int ni = 0; ni < 4; ++ni)
          acc[mi][ni] = mfma_bf16(af[mi], bfm[ni], acc[mi][ni]);
    }
  } else {
    auto stage = [&](int t) {
      bf16* a = sA[t % 3];
      bf16* bb = sB[t % 3];
      gl_lds16(Ag1 + t * 32, a + o1);
      gl_lds16(Ag2 + t * 32, a + o2);
      gl_lds16(Bg1 + t * 32, bb + o1);
    };
    stage(0);
    stage(1);
    for (int kt = 0; kt < kIters; ++kt) {
      if (kt + 1 < kIters)
        wait_vm_barrier<3>();
      else
        wait_vm_barrier<0>();
      if (kt + 2 < kIters) stage(kt + 2);
      const bf16* cA = sA[kt % 3];
      const bf16* cB = sB[kt % 3];
      bf16x8 af[MI], bfm[4];
#pragma unroll
      for (int i = 0; i < MI; ++i)
        af[i] = *(const bf16x8*)(cA +
                                 ((wr * 32 + i * 16 + lc) * 32 + quad * 8));
#pragma unroll
      for (int i = 0; i < 4; ++i)
        bfm[i] = *(const bf16x8*)(cB + ((i * 16 + lc) * 32 + quad * 8));
#pragma unroll
      for (int mi = 0; mi < MI; ++mi)
#pragma unroll
        for (int ni = 0; ni < 4; ++ni)
          acc[mi][ni] = mfma_bf16(af[mi], bfm[ni], acc[mi][ni]);
    }
  }

  // ---------------- epilogue ----------------
  if constexpr (MODE == 0) {
    if (n0 >= 1024) {
      // V panel: write transposed into Vt[(b*8+h)][d][s]
#pragma unroll
      for (int mi = 0; mi < MI; ++mi) {
        const int row0 = m0 + wr * (16 * MI) + mi * 16 + quad * 4;
        const int bb = row0 >> 11, s0 = row0 & 2047;
#pragma unroll
        for (int ni = 0; ni < 4; ++ni) {
          const int col = n0 + wc * 64 + ni * 16 + lc;  // 1024..1535
          const int hh = (col >> 6) & 7, d = col & 63;
          bf16x4 pb;
#pragma unroll
          for (int r = 0; r < 4; ++r) pb[r] = (bf16)acc[mi][ni][r];
          *(bf16x4*)(vt + ((size_t)((bb * 8 + hh) * 64 + d)) * 2048 + s0) = pb;
        }
      }
      return;
    }
  }
  const float qscale = (MODE == 0 && n0 < 512) ? SCALE_L2E : 1.0f;
#pragma unroll
  for (int mi = 0; mi < MI; ++mi) {
#pragma unroll
    for (int r = 0; r < 4; ++r) {
      const int row = m0 + wr * (16 * MI) + mi * 16 + quad * 4 + r;
#pragma unroll
      for (int ni = 0; ni < 4; ++ni) {
        const int col = n0 + wc * 64 + ni * 16 + lc;
        const size_t idx = (size_t)row * N + col;
        float v = acc[mi][ni][r];
        if (MODE == 0) v *= qscale;
        if (MODE == 1) v += resf[idx];
        if (MODE == 2) v = gelu_tanh(v + bias[col]);
        if (MODE == 3) v += bias[col] + (float)resb[idx];
        C[idx] = (OutT)v;
      }
    }
  }
}

// ---------------- gemm256v2: 256x256 tile for FFN1 (gelu+bias) -------------
__global__ __launch_bounds__(512, 2) void gemm256v2(
    const bf16* __restrict__ A, const bf16* __restrict__ Bt,
    bf16* __restrict__ C, const float* __restrict__ bias, int M, int N,
    int K) {
  __shared__ __align__(16) bf16 sA[4][8192];
  __shared__ __align__(16) bf16 sB[4][8192];
  const int tid = threadIdx.x;
  const int lane = tid & 63;
  const int quad = lane >> 4, lc = lane & 15;
  const int w8 = tid >> 6;
  const int wm = w8 >> 2, wn = w8 & 3;
  int bxs, bys;
  xcd_remap(bxs, bys);
  const int m0 = bys * 256, n0 = bxs * 256;

  const int srow0 = tid >> 2;
  const int cpos = tid & 3;

  f32x4 acc[8][4];
#pragma unroll
  for (int mi = 0; mi < 8; ++mi)
#pragma unroll
    for (int ni = 0; ni < 4; ++ni) acc[mi][ni] = (f32x4){0.f, 0.f, 0.f, 0.f};

  auto stage = [&](int t) {
    bf16* a = sA[t & 3];
    bf16* bb = sB[t & 3];
    const int k0 = t * 32;
#pragma unroll
    for (int c = 0; c < 2; ++c) {
      const int row = c * 128 + srow0;
      const int sc = (cpos ^ (row & 3)) * 8;  // source chunk (elements)
      gl_lds16(A + (size_t)(m0 + row) * K + k0 + sc, a + c * 4096 + tid * 8);
      gl_lds16(Bt + (size_t)(n0 + row) * K + k0 + sc, bb + c * 4096 + tid * 8);
    }
  };

  const int kIters = K >> 5;  // 16 for FFN1
  stage(0);
  stage(1);
  stage(2);  // 12 loads outstanding

  const int cxq = (quad ^ (lc & 3)) << 3;

  for (int kt = 0; kt < kIters; ++kt) {
    const int left = kIters - 1 - kt;
    if (left >= 2)
      wait_vm_barrier<8>();
    else if (left == 1)
      wait_vm_barrier<4>();
    else
      wait_vm_barrier<0>();
    if (kt + 3 < kIters) stage(kt + 3);
    const bf16* cA = sA[kt & 3];
    const bf16* cB = sB[kt & 3];

    bf16x8 af[8], bfm[4];
#pragma unroll
    for (int i = 0; i < 4; ++i)
      af[i] = *(const bf16x8*)(cA + (wm * 128 + i * 16 + lc) * 32 + cxq);
#pragma unroll
    for (int j = 0; j < 4; ++j)
      bfm[j] = *(const bf16x8*)(cB + (wn * 64 + j * 16 + lc) * 32 + cxq);
    __builtin_amdgcn_s_barrier();  // raw: no vmcnt drain
    __builtin_amdgcn_s_setprio(1);
#pragma unroll
    for (int mi = 0; mi < 4; ++mi)
#pragma unroll
      for (int ni = 0; ni < 4; ++ni)
        acc[mi][ni] = mfma_bf16(af[mi], bfm[ni], acc[mi][ni]);
    __builtin_amdgcn_s_setprio(0);
#pragma unroll
    for (int i = 4; i < 8; ++i)
      af[i] = *(const bf16x8*)(cA + (wm * 128 + i * 16 + lc) * 32 + cxq);
    __builtin_amdgcn_s_barrier();
    __builtin_amdgcn_s_setprio(1);
#pragma unroll
    for (int mi = 4; mi < 8; ++mi)
#pragma unroll
      for (int ni = 0; ni < 4; ++ni)
        acc[mi][ni] = mfma_bf16(af[mi], bfm[ni], acc[mi][ni]);
    __builtin_amdgcn_s_setprio(0);
  }

#pragma unroll
  for (int mi = 0; mi < 8; ++mi) {
#pragma unroll
    for (int r = 0; r < 4; ++r) {
      const int row = m0 + wm * 128 + mi * 16 + quad * 4 + r;
#pragma unroll
      for (int ni = 0; ni < 4; ++ni) {
        const int col = n0 + wn * 64 + ni * 16 + lc;
        C[(size_t)row * N + col] = (bf16)gelu_tanh(acc[mi][ni][r] + bias[col]);
      }
    }
  }
}

// ---------------- flash attention (R22 struct + rsum via MFMA) -------------
// grid (16, 32), 256 thr = 4 waves, wave owns 32 q-rows. XCD swizzle: each
// XCD owns 4 bh (K/V 2MB, L2-resident). 3-ring K and V, distance-2 prefetch,
// counted vmcnt(4)+s_barrier. Softmax p = exp2(st) (Q pre-scaled, no max).
// Row-sum via mfma(paw, ONES): sums both hi halves internally; racc[r] is
// the denominator for row qloc(r,hi) directly (no shuffles).
__global__ __launch_bounds__(256, 2) void flash_attn(
    const bf16* __restrict__ QKV, const bf16* __restrict__ Vt,
    bf16* __restrict__ O) {
  const int tid = threadIdx.x;
  const int lane = tid & 63, wave = tid >> 6;
  const int lo5 = lane & 31, hi = lane >> 5;
  const int lin = blockIdx.y * 16 + blockIdx.x;
  const int xcd = lin & 7, slot = lin >> 3;
  const int bh = xcd * 4 + (slot >> 4);
  const int qt = slot & 15;
  const int b = bh >> 3, h = bh & 7;
  const int q0 = qt * 128 + wave * 32;

  __shared__ __align__(16) bf16 sK[3][4096];
  __shared__ __align__(16) bf16 sV[3][4096];

  // Q as B-operand: qf[i] holds Q[q0+lo5][i*16 + hi*8 + j] (pre-scaled)
  const bf16* Qrow = QKV + (size_t)(b * 2048 + q0 + lo5) * 1536 + h * 64;
  bf16x8 qf[4];
#pragma unroll
  for (int i = 0; i < 4; ++i) qf[i] = *(const bf16x8*)(Qrow + i * 16 + hi * 8);

  // staging: wave stages rows wave*16..+15; chunk swizzle pos^(row&7)
  const int colsw = (((lane & 7) ^ (lane >> 3)) << 3);
  const bf16* Kg0 = QKV + (size_t)b * 2048 * 1536 + 512 + (size_t)h * 64 +
                    (size_t)(wave * 16 + (lane >> 3)) * 1536 + colsw;
  const bf16* Vg0 = Vt + (size_t)bh * 64 * 2048 +
                    (size_t)(wave * 16 + (lane >> 3)) * 2048 + colsw;
  const int stag = wave * 1024;
  const int m7 = lo5 & 7;

  f32x16 oacc[2], racc;
  oacc[0] = (f32x16)(0.f);
  oacc[1] = (f32x16)(0.f);
  racc = (f32x16)(0.f);

  bf16x8 ones;
#pragma unroll
  for (int i = 0; i < 8; ++i) ones[i] = (bf16)1.0f;

  auto stage = [&](int t) {
    bf16* dk = sK[t % 3] + stag;
    bf16* dv = sV[t % 3] + stag;
    gl_lds16(Kg0 + (size_t)t * 64 * 1536, dk);
    gl_lds16(Kg0 + (size_t)(t * 64 + 8) * 1536, dk + 512);
    gl_lds16(Vg0 + t * 64, dv);
    gl_lds16(Vg0 + t * 64 + 8 * 2048, dv + 512);
  };
  stage(0);
  stage(1);  // 8 loads in flight

  bf16x8 paw[4];

  // softmax: st -> paw[2*hl], paw[2*hl+1]. P = exp2(st). No sum here --
  // the row-sum rides the matrix pipe via mfma(paw, ones).
  auto softmax = [&](const f32x16& st, int hl) {
    unsigned int q32[4][2];
#pragma unroll
    for (int g = 0; g < 4; ++g) {
      bf16x4 pb;
      pb[0] = (bf16)EXP2(st[4 * g + 0]);
      pb[1] = (bf16)EXP2(st[4 * g + 1]);
      pb[2] = (bf16)EXP2(st[4 * g + 2]);
      pb[3] = (bf16)EXP2(st[4 * g + 3]);
      u32x2 w2 = __builtin_bit_cast(u32x2, pb);
      q32[g][0] = w2[0];
      q32[g][1] = w2[1];
    }
#pragma unroll
    for (int t = 0; t < 2; ++t) {
      unsigned int a0 = q32[2 * t][0], a1 = q32[2 * t][1];
      unsigned int b0 = q32[2 * t + 1][0], b1 = q32[2 * t + 1][1];
      plswap(a0, b0);
      plswap(a1, b1);
      u32x4 f = {a0, a1, b0, b1};
      paw[hl * 2 + t] = __builtin_bit_cast(bf16x8, f);
    }
  };

  for (int kt = 0; kt < 32; ++kt) {
    if (kt == 31)
      wait_vm_barrier<0>();
    else
      wait_vm_barrier<4>();
    if (kt + 2 < 32) stage(kt + 2);
    const bf16* cK = sK[kt % 3];
    const bf16* cV = sV[kt % 3];

    // Preload V then K fragments (DS in-order: K-wait implies V done).
    bf16x8 vf[2][4], kf[2][4];
#pragma unroll
    for (int dh = 0; dh < 2; ++dh) {
      const int Rd = dh * 32 + lo5;
#pragma unroll
      for (int w = 0; w < 4; ++w)
        vf[dh][w] =
            *(const bf16x8*)(cV + Rd * 64 + (((2 * w + hi) ^ m7) << 3));
    }
#pragma unroll
    for (int hl = 0; hl < 2; ++hl) {
      const int R = hl * 32 + lo5;
#pragma unroll
      for (int i = 0; i < 4; ++i)
        kf[hl][i] =
            *(const bf16x8*)(cK + R * 64 + (((2 * i + hi) ^ m7) << 3));
    }

    // Both QK chains interleaved (independent accumulators).
    f32x16 st0 = (f32x16)(0.f), st1 = (f32x16)(0.f);
    __builtin_amdgcn_s_setprio(1);
#pragma unroll
    for (int i = 0; i < 4; ++i) {
      st0 = mfma32x16(kf[0][i], qf[i], st0);
      st1 = mfma32x16(kf[1][i], qf[i], st1);
    }
    __builtin_amdgcn_s_setprio(0);

    // softmax(hl0) -> paw[0..1]; PV w0,w1 (+rsum MFMA) overlaps softmax(hl1).
    softmax(st0, 0);
#pragma unroll
    for (int w = 0; w < 2; ++w) {
      oacc[0] = mfma32x16(paw[w], vf[0][w], oacc[0]);
      oacc[1] = mfma32x16(paw[w], vf[1][w], oacc[1]);
      racc = mfma32x16(paw[w], ones, racc);
    }
    softmax(st1, 1);
    __builtin_amdgcn_s_setprio(1);
#pragma unroll
    for (int w = 2; w < 4; ++w) {
      oacc[0] = mfma32x16(paw[w], vf[0][w], oacc[0]);
      oacc[1] = mfma32x16(paw[w], vf[1][w], oacc[1]);
      racc = mfma32x16(paw[w], ones, racc);
    }
    __builtin_amdgcn_s_setprio(0);
  }

  // normalize; store. racc[r] = full denominator for row qloc(r,hi).
  const size_t obase = (size_t)(b * 2048 + q0) * 512 + h * 64;
#pragma unroll
  for (int r = 0; r < 16; ++r) {
    const int qloc = (r & 3) + 8 * (r >> 2) + 4 * hi;
    const float inv = 1.0f / racc[r];
#pragma unroll
    for (int dh = 0; dh < 2; ++dh)
      O[obase + (size_t)qloc * 512 + dh * 32 + lo5] =
          (bf16)(oacc[dh][r] * inv);
  }
}

// ---------------- prep: convert x + all weight transposes ------------------
__global__ __launch_bounds__(256) void prep(
    const float* __restrict__ x, const float* __restrict__ Wq,
    const float* __restrict__ Wk, const float* __restrict__ Wv,
    const float* __restrict__ Wo, const float* __restrict__ W1,
    const float* __restrict__ W2, bf16* __restrict__ xb,
    bf16* __restrict__ WqkvT, bf16* __restrict__ WoT, bf16* __restrict__ W1T,
    bf16* __restrict__ W2T) {
  const int bid = blockIdx.x;
  if (bid < 4096) {
    const size_t i = ((size_t)bid * 256 + threadIdx.x) * 4;
    const float4 v = *(const float4*)(x + i);
    bf16x4 o;
    o[0] = (bf16)v.x; o[1] = (bf16)v.y; o[2] = (bf16)v.z; o[3] = (bf16)v.w;
    *(bf16x4*)(xb + i) = o;
    return;
  }
  const int t = bid - 4096;
  const float* in;
  bf16* out;
  int in_ld, out_ld, bx, by;
  if (t < 1024) {
    const int q = t >> 8, r = t & 255;
    bx = r & 15; by = r >> 4; in_ld = 512; out_ld = 512;
    in = (q == 0) ? Wq : (q == 1) ? Wk : (q == 2) ? Wv : Wo;
    out = (q == 0) ? WqkvT
          : (q == 1) ? WqkvT + 512 * 512
          : (q == 2) ? WqkvT + 2 * 512 * 512
                     : WoT;
  } else if (t < 2048) {
    const int r = t - 1024;
    bx = r & 63; by = r >> 6; in_ld = 2048; out_ld = 512;
    in = W1; out = W1T;
  } else {
    const int r = t - 2048;
    bx = r & 15; by = r >> 4; in_ld = 512; out_ld = 2048;
    in = W2; out = W2T;
  }
  __shared__ __align__(16) bf16 tl[32][33];
  const int tx = threadIdx.x & 31, ty = threadIdx.x >> 5;
  const int n0 = bx * 32, k0 = by * 32;
#pragma unroll
  for (int i = 0; i < 4; ++i)
    tl[ty + 8 * i][tx] = (bf16)in[(size_t)(k0 + ty + 8 * i) * in_ld + n0 + tx];
  __syncthreads();
#pragma unroll
  for (int i = 0; i < 4; ++i)
    out[(size_t)(n0 + ty + 8 * i) * out_ld + k0 + tx] = tl[tx][ty + 8 * i];
}

extern "C" void kernel_launch(void* const* d_in, const int* in_sizes, int n_in,
                              void* d_out, int out_size, void* d_ws,
                              size_t ws_size, hipStream_t stream) {
  const float* x = (const float*)d_in[0];
  const float* Wq = (const float*)d_in[1];
  const float* Wk = (const float*)d_in[2];
  const float* Wv = (const float*)d_in[3];
  const float* Wo = (const float*)d_in[4];
  const float* W1 = (const float*)d_in[5];
  const float* b1 = (const float*)d_in[6];
  const float* W2 = (const float*)d_in[7];
  const float* b2 = (const float*)d_in[8];
  float* out = (float*)d_out;  // fp32 output

  char* ws = (char*)d_ws;
  size_t off = 0;
  auto alloc = [&](size_t bytes) {
    char* p = ws + off;
    off += (bytes + 255) & ~(size_t)255;
    return p;
  };
  bf16* WqkvT = (bf16*)alloc(1536ULL * 512 * 2);
  bf16* WoT = (bf16*)alloc(512ULL * 512 * 2);
  bf16* W1T = (bf16*)alloc(2048ULL * 512 * 2);
  bf16* W2T = (bf16*)alloc(512ULL * 2048 * 2);
  bf16* xb = (bf16*)alloc(8192ULL * 512 * 2);      // bf16(x); reused as x2
  bf16* QKV = (bf16*)alloc(8192ULL * 1536 * 2);    // [8192][1536]
  bf16* Vt = (bf16*)alloc(32ULL * 64 * 2048 * 2);  // [B*H][64][2048]
  bf16* attn = (bf16*)alloc(8192ULL * 512 * 2);
  bf16* x2 = xb;     // xb dead after QKV gemm
  bf16* hbuf = QKV;  // FFN hidden [8192][2048] = QKV+Vt region (dead by FFN1)

  const dim3 tb(256);
  prep<<<dim3(7168), tb, 0, stream>>>(x, Wq, Wk, Wv, Wo, W1, W2, xb, WqkvT,
                                      WoT, W1T, W2T);
  // QKV gemm: Q panel pre-scaled, V panel written transposed into Vt.
  gemm_bt<0, bf16, 128><<<dim3(12, 64), tb, 0, stream>>>(
      xb, WqkvT, QKV, nullptr, nullptr, nullptr, Vt, 8192, 1536, 512);
  flash_attn<<<dim3(16, 32), tb, 0, stream>>>(QKV, Vt, attn);
  gemm_bt<1, bf16, 64><<<dim3(8, 64), tb, 0, stream>>>(
      attn, WoT, x2, nullptr, x, nullptr, nullptr, 8192, 512, 512);
  gemm256v2<<<dim3(8, 32), dim3(512), 0, stream>>>(x2, W1T, hbuf, b1, 8192,
                                                   2048, 512);
  gemm_bt<3, float, 64><<<dim3(8, 64), tb, 0, stream>>>(
      hbuf, W2T, out, b2, nullptr, x2, nullptr, 8192, 512, 2048);
}

// Round 16
// 236.525 us; speedup vs baseline: 1.0240x; 1.0240x over previous
//
#include <hip/hip_runtime.h>
#include <hip/hip_bf16.h>

// EncoderLayer B=4,S=2048,D=512,H=8,HD=64,E=4. Inputs fp32, OUTPUT fp32.
// R28: exact R22 restore (session best 239.0; R26 QKV-3ring neutral, R27
// rsum-via-MFMA regressed: VALU wasn't binding -- racc added a serial MFMA
// chain inside the saturated PV burst) + one safe traffic cut:
//  - Wo GEMM (MODE 1) residual now reads xb (bf16, 8MB) instead of x (fp32,
//    16MB). xb is still live (dead only after this kernel) and aliases the
//    output x2: per-thread read-before-write on the same idx, each idx
//    owned by exactly one thread -> race-free. Residual rounding (<=2^-9
//    rel) negligible vs 0.03125 absmax budget.
// Config: flash R22 (3-ring K/V, vmcnt(4), exp2 softmax, XCD swizzle),
// QKV TN=128 2-buffer + Q-scale fold + Vt-fused epilogue, gemm256v2 FFN1,
// TN=64 3-ring Wo/FFN2, prep.

typedef __bf16 bf16;
typedef __attribute__((ext_vector_type(8))) __bf16 bf16x8;
typedef __attribute__((ext_vector_type(4))) __bf16 bf16x4;
typedef __attribute__((ext_vector_type(4))) float f32x4;
typedef __attribute__((ext_vector_type(16))) float f32x16;
typedef __attribute__((ext_vector_type(2))) unsigned int u32x2;
typedef __attribute__((ext_vector_type(4))) unsigned int u32x4;

#define LOG2E 1.4426950408889634f
#define SCORE_SCALE 0.044194173824159216f /* 512^-0.5 (D^-0.25 on q AND k) */
#define SCALE_L2E (SCORE_SCALE * LOG2E)   /* folded into stored Q */

#if __has_builtin(__builtin_amdgcn_exp2f)
#define EXP2(x) __builtin_amdgcn_exp2f(x)
#else
#define EXP2(x) exp2f(x)
#endif

__device__ __forceinline__ void gl_lds16(const bf16* g, bf16* l) {
  __builtin_amdgcn_global_load_lds(
      (const __attribute__((address_space(1))) unsigned int*)g,
      (__attribute__((address_space(3))) unsigned int*)l, 16, 0, 0);
}

template <int N>
__device__ __forceinline__ void wait_vm_barrier() {
  if constexpr (N == 0)
    asm volatile("s_waitcnt vmcnt(0)\ns_barrier" ::: "memory");
  else if constexpr (N == 3)
    asm volatile("s_waitcnt vmcnt(3)\ns_barrier" ::: "memory");
  else if constexpr (N == 4)
    asm volatile("s_waitcnt vmcnt(4)\ns_barrier" ::: "memory");
  else if constexpr (N == 8)
    asm volatile("s_waitcnt vmcnt(8)\ns_barrier" ::: "memory");
}

__device__ __forceinline__ float gelu_tanh(float x) {
  float u = 0.7978845608028654f * (x + 0.044715f * x * x * x);
  float e = EXP2(u * (2.0f * LOG2E));   // e^(2u)
  float th = 1.0f - 2.0f / (e + 1.0f);  // tanh(u), saturates at +-1
  return 0.5f * x * (1.0f + th);
}

__device__ __forceinline__ f32x4 mfma_bf16(bf16x8 a, bf16x8 b, f32x4 c) {
  return __builtin_amdgcn_mfma_f32_16x16x32_bf16(a, b, c, 0, 0, 0);
}
__device__ __forceinline__ f32x16 mfma32x16(bf16x8 a, bf16x8 b, f32x16 c) {
  return __builtin_amdgcn_mfma_f32_32x32x16_bf16(a, b, c, 0, 0, 0);
}

// v_permlane32_swap_b32: vdst.hi32lanes <-> src.lo32lanes (writes BOTH).
__device__ __forceinline__ void plswap(unsigned int& a, unsigned int& b) {
  asm volatile("v_permlane32_swap_b32 %0, %1" : "+v"(a), "+v"(b));
}

// Chunked bijective XCD remap (requires nwg%8==0).
__device__ __forceinline__ void xcd_remap(int& bx, int& by) {
  const int gx = gridDim.x;
  const int nwg = gx * gridDim.y;
  const int lin = blockIdx.y * gx + blockIdx.x;
  const int id = (lin & 7) * (nwg >> 3) + (lin >> 3);
  bx = id % gx;
  by = id / gx;
}

// ---------------- GEMM: C[M,N] = A[M,K] @ Bt[N,K]^T ------------------------
// TN=128: 2-buffer __syncthreads (R11/R22). TN=64: 3-ring counted vmcnt(3).
// MODE 0: Q panel (n0<512) scaled by SCALE_L2E; V panel (n0>=1024) written
// transposed into vt. MODE 1: bf16 residual resb (may alias C; per-thread
// read-before-write on same idx). MODE 3: bias + bf16 residual.
template <int MODE, typename OutT, int TN>
__global__ __launch_bounds__(256, 2) void gemm_bt(
    const bf16* __restrict__ A, const bf16* __restrict__ Bt,
    OutT* __restrict__ C, const float* __restrict__ bias,
    const bf16* __restrict__ resb, bf16* __restrict__ vt, int M, int N,
    int K) {
  constexpr int MI = (TN == 128) ? 4 : 2;
  constexpr int NBUF = (TN == 128) ? 2 : 3;
  __shared__ __align__(16) bf16 sA[NBUF][128 * 32];
  __shared__ __align__(16) bf16 sB[NBUF][TN * 32];
  const int tid = threadIdx.x;
  const int lane = tid & 63;
  const int quad = lane >> 4, lc = lane & 15;
  const int wave = tid >> 6;
  const int wr = (TN == 128) ? (wave >> 1) : wave;
  const int wc = (TN == 128) ? (wave & 1) : 0;
  int bxs, bys;
  xcd_remap(bxs, bys);
  const int m0 = bys * 128, n0 = bxs * TN;

  const int srow = tid >> 2;
  const int kc = (tid & 3) * 8;
  const bf16* Ag1 = A + (size_t)(m0 + srow) * K + kc;
  const bf16* Ag2 = A + (size_t)(m0 + 64 + srow) * K + kc;
  const bf16* Bg1 = Bt + (size_t)(n0 + srow) * K + kc;
  const bf16* Bg2 = Bt + (size_t)(n0 + 64 + srow) * K + kc;
  const int o1 = tid * 8, o2 = (tid + 256) * 8;

  f32x4 acc[MI][4];
#pragma unroll
  for (int mi = 0; mi < MI; ++mi)
#pragma unroll
    for (int ni = 0; ni < 4; ++ni) acc[mi][ni] = (f32x4){0.f, 0.f, 0.f, 0.f};

  const int kIters = K >> 5;

  if constexpr (TN == 128) {
    gl_lds16(Ag1, sA[0] + o1);
    gl_lds16(Ag2, sA[0] + o2);
    gl_lds16(Bg1, sB[0] + o1);
    gl_lds16(Bg2, sB[0] + o2);
    Ag1 += 32; Ag2 += 32; Bg1 += 32; Bg2 += 32;

    for (int kt = 0; kt < kIters; ++kt) {
      __syncthreads();
      const bf16* cA = sA[kt & 1];
      const bf16* cB = sB[kt & 1];
      if (kt + 1 < kIters) {
        bf16* nA = sA[(kt + 1) & 1];
        bf16* nB = sB[(kt + 1) & 1];
        gl_lds16(Ag1, nA + o1);
        gl_lds16(Ag2, nA + o2);
        gl_lds16(Bg1, nB + o1);
        gl_lds16(Bg2, nB + o2);
        Ag1 += 32; Ag2 += 32; Bg1 += 32; Bg2 += 32;
      }
      bf16x8 af[MI], bfm[4];
#pragma unroll
      for (int i = 0; i < MI; ++i)
        af[i] = *(const bf16x8*)(cA +
                                 ((wr * 64 + i * 16 + lc) * 32 + quad * 8));
#pragma unroll
      for (int i = 0; i < 4; ++i)
        bfm[i] =
            *(const bf16x8*)(cB + ((wc * 64 + i * 16 + lc) * 32 + quad * 8));
#pragma unroll
      for (int mi = 0; mi < MI; ++mi)
#pragma unroll
        for (int ni = 0; ni < 4; ++ni)
          acc[mi][ni] = mfma_bf16(af[mi], bfm[ni], acc[mi][ni]);
    }
  } else {
    auto stage = [&](int t) {
      bf16* a = sA[t % 3];
      bf16* bb = sB[t % 3];
      gl_lds16(Ag1 + t * 32, a + o1);
      gl_lds16(Ag2 + t * 32, a + o2);
      gl_lds16(Bg1 + t * 32, bb + o1);
    };
    stage(0);
    stage(1);
    for (int kt = 0; kt < kIters; ++kt) {
      if (kt + 1 < kIters)
        wait_vm_barrier<3>();
      else
        wait_vm_barrier<0>();
      if (kt + 2 < kIters) stage(kt + 2);
      const bf16* cA = sA[kt % 3];
      const bf16* cB = sB[kt % 3];
      bf16x8 af[MI], bfm[4];
#pragma unroll
      for (int i = 0; i < MI; ++i)
        af[i] = *(const bf16x8*)(cA +
                                 ((wr * 32 + i * 16 + lc) * 32 + quad * 8));
#pragma unroll
      for (int i = 0; i < 4; ++i)
        bfm[i] = *(const bf16x8*)(cB + ((i * 16 + lc) * 32 + quad * 8));
#pragma unroll
      for (int mi = 0; mi < MI; ++mi)
#pragma unroll
        for (int ni = 0; ni < 4; ++ni)
          acc[mi][ni] = mfma_bf16(af[mi], bfm[ni], acc[mi][ni]);
    }
  }

  // ---------------- epilogue ----------------
  if constexpr (MODE == 0) {
    if (n0 >= 1024) {
      // V panel: write transposed into Vt[(b*8+h)][d][s]
#pragma unroll
      for (int mi = 0; mi < MI; ++mi) {
        const int row0 = m0 + wr * (16 * MI) + mi * 16 + quad * 4;
        const int bb = row0 >> 11, s0 = row0 & 2047;
#pragma unroll
        for (int ni = 0; ni < 4; ++ni) {
          const int col = n0 + wc * 64 + ni * 16 + lc;  // 1024..1535
          const int hh = (col >> 6) & 7, d = col & 63;
          bf16x4 pb;
#pragma unroll
          for (int r = 0; r < 4; ++r) pb[r] = (bf16)acc[mi][ni][r];
          *(bf16x4*)(vt + ((size_t)((bb * 8 + hh) * 64 + d)) * 2048 + s0) = pb;
        }
      }
      return;
    }
  }
  const float qscale = (MODE == 0 && n0 < 512) ? SCALE_L2E : 1.0f;
#pragma unroll
  for (int mi = 0; mi < MI; ++mi) {
#pragma unroll
    for (int r = 0; r < 4; ++r) {
      const int row = m0 + wr * (16 * MI) + mi * 16 + quad * 4 + r;
#pragma unroll
      for (int ni = 0; ni < 4; ++ni) {
        const int col = n0 + wc * 64 + ni * 16 + lc;
        const size_t idx = (size_t)row * N + col;
        float v = acc[mi][ni][r];
        if (MODE == 0) v *= qscale;
        if (MODE == 1) v += (float)resb[idx];
        if (MODE == 2) v = gelu_tanh(v + bias[col]);
        if (MODE == 3) v += bias[col] + (float)resb[idx];
        C[idx] = (OutT)v;
      }
    }
  }
}

// ---------------- gemm256v2: 256x256 tile for FFN1 (gelu+bias) -------------
__global__ __launch_bounds__(512, 2) void gemm256v2(
    const bf16* __restrict__ A, const bf16* __restrict__ Bt,
    bf16* __restrict__ C, const float* __restrict__ bias, int M, int N,
    int K) {
  __shared__ __align__(16) bf16 sA[4][8192];
  __shared__ __align__(16) bf16 sB[4][8192];
  const int tid = threadIdx.x;
  const int lane = tid & 63;
  const int quad = lane >> 4, lc = lane & 15;
  const int w8 = tid >> 6;
  const int wm = w8 >> 2, wn = w8 & 3;
  int bxs, bys;
  xcd_remap(bxs, bys);
  const int m0 = bys * 256, n0 = bxs * 256;

  const int srow0 = tid >> 2;
  const int cpos = tid & 3;

  f32x4 acc[8][4];
#pragma unroll
  for (int mi = 0; mi < 8; ++mi)
#pragma unroll
    for (int ni = 0; ni < 4; ++ni) acc[mi][ni] = (f32x4){0.f, 0.f, 0.f, 0.f};

  auto stage = [&](int t) {
    bf16* a = sA[t & 3];
    bf16* bb = sB[t & 3];
    const int k0 = t * 32;
#pragma unroll
    for (int c = 0; c < 2; ++c) {
      const int row = c * 128 + srow0;
      const int sc = (cpos ^ (row & 3)) * 8;  // source chunk (elements)
      gl_lds16(A + (size_t)(m0 + row) * K + k0 + sc, a + c * 4096 + tid * 8);
      gl_lds16(Bt + (size_t)(n0 + row) * K + k0 + sc, bb + c * 4096 + tid * 8);
    }
  };

  const int kIters = K >> 5;  // 16 for FFN1
  stage(0);
  stage(1);
  stage(2);  // 12 loads outstanding

  const int cxq = (quad ^ (lc & 3)) << 3;

  for (int kt = 0; kt < kIters; ++kt) {
    const int left = kIters - 1 - kt;
    if (left >= 2)
      wait_vm_barrier<8>();
    else if (left == 1)
      wait_vm_barrier<4>();
    else
      wait_vm_barrier<0>();
    if (kt + 3 < kIters) stage(kt + 3);
    const bf16* cA = sA[kt & 3];
    const bf16* cB = sB[kt & 3];

    bf16x8 af[8], bfm[4];
#pragma unroll
    for (int i = 0; i < 4; ++i)
      af[i] = *(const bf16x8*)(cA + (wm * 128 + i * 16 + lc) * 32 + cxq);
#pragma unroll
    for (int j = 0; j < 4; ++j)
      bfm[j] = *(const bf16x8*)(cB + (wn * 64 + j * 16 + lc) * 32 + cxq);
    __builtin_amdgcn_s_barrier();  // raw: no vmcnt drain
    __builtin_amdgcn_s_setprio(1);
#pragma unroll
    for (int mi = 0; mi < 4; ++mi)
#pragma unroll
      for (int ni = 0; ni < 4; ++ni)
        acc[mi][ni] = mfma_bf16(af[mi], bfm[ni], acc[mi][ni]);
    __builtin_amdgcn_s_setprio(0);
#pragma unroll
    for (int i = 4; i < 8; ++i)
      af[i] = *(const bf16x8*)(cA + (wm * 128 + i * 16 + lc) * 32 + cxq);
    __builtin_amdgcn_s_barrier();
    __builtin_amdgcn_s_setprio(1);
#pragma unroll
    for (int mi = 4; mi < 8; ++mi)
#pragma unroll
      for (int ni = 0; ni < 4; ++ni)
        acc[mi][ni] = mfma_bf16(af[mi], bfm[ni], acc[mi][ni]);
    __builtin_amdgcn_s_setprio(0);
  }

#pragma unroll
  for (int mi = 0; mi < 8; ++mi) {
#pragma unroll
    for (int r = 0; r < 4; ++r) {
      const int row = m0 + wm * 128 + mi * 16 + quad * 4 + r;
#pragma unroll
      for (int ni = 0; ni < 4; ++ni) {
        const int col = n0 + wn * 64 + ni * 16 + lc;
        C[(size_t)row * N + col] = (bf16)gelu_tanh(acc[mi][ni][r] + bias[col]);
      }
    }
  }
}

// ---------------- flash attention (exact R22 version) ----------------------
// grid (16, 32), 256 thr = 4 waves, wave owns 32 q-rows. XCD swizzle: each
// XCD owns 4 bh (K/V 2MB, L2-resident). 3-ring K and V, distance-2 prefetch,
// counted vmcnt(4)+s_barrier. Softmax: p = exp2(st) (Q pre-scaled; no
// FIXED_M -- uniform factor cancels in O = PV/rsum).
__global__ __launch_bounds__(256, 2) void flash_attn(
    const bf16* __restrict__ QKV, const bf16* __restrict__ Vt,
    bf16* __restrict__ O) {
  const int tid = threadIdx.x;
  const int lane = tid & 63, wave = tid >> 6;
  const int lo5 = lane & 31, hi = lane >> 5;
  const int lin = blockIdx.y * 16 + blockIdx.x;
  const int xcd = lin & 7, slot = lin >> 3;
  const int bh = xcd * 4 + (slot >> 4);
  const int qt = slot & 15;
  const int b = bh >> 3, h = bh & 7;
  const int q0 = qt * 128 + wave * 32;

  __shared__ __align__(16) bf16 sK[3][4096];
  __shared__ __align__(16) bf16 sV[3][4096];

  // Q as B-operand: qf[i] holds Q[q0+lo5][i*16 + hi*8 + j] (pre-scaled)
  const bf16* Qrow = QKV + (size_t)(b * 2048 + q0 + lo5) * 1536 + h * 64;
  bf16x8 qf[4];
#pragma unroll
  for (int i = 0; i < 4; ++i) qf[i] = *(const bf16x8*)(Qrow + i * 16 + hi * 8);

  // staging: wave stages rows wave*16..+15; chunk swizzle pos^(row&7)
  const int colsw = (((lane & 7) ^ (lane >> 3)) << 3);
  const bf16* Kg0 = QKV + (size_t)b * 2048 * 1536 + 512 + (size_t)h * 64 +
                    (size_t)(wave * 16 + (lane >> 3)) * 1536 + colsw;
  const bf16* Vg0 = Vt + (size_t)bh * 64 * 2048 +
                    (size_t)(wave * 16 + (lane >> 3)) * 2048 + colsw;
  const int stag = wave * 1024;
  const int m7 = lo5 & 7;

  f32x16 oacc[2];
  oacc[0] = (f32x16)(0.f);
  oacc[1] = (f32x16)(0.f);
  float rs0 = 0.f, rs1 = 0.f, rs2 = 0.f, rs3 = 0.f;

  auto stage = [&](int t) {
    bf16* dk = sK[t % 3] + stag;
    bf16* dv = sV[t % 3] + stag;
    gl_lds16(Kg0 + (size_t)t * 64 * 1536, dk);
    gl_lds16(Kg0 + (size_t)(t * 64 + 8) * 1536, dk + 512);
    gl_lds16(Vg0 + t * 64, dv);
    gl_lds16(Vg0 + t * 64 + 8 * 2048, dv + 512);
  };
  stage(0);
  stage(1);  // 8 loads in flight

  bf16x8 paw[4];

  // softmax: st -> paw[2*hl], paw[2*hl+1]; partial sums. P = exp2(st).
  auto softmax = [&](const f32x16& st, int hl) {
    unsigned int q32[4][2];
#pragma unroll
    for (int g = 0; g < 4; ++g) {
      bf16x4 pb;
      float p0 = EXP2(st[4 * g + 0]);
      float p1 = EXP2(st[4 * g + 1]);
      float p2 = EXP2(st[4 * g + 2]);
      float p3 = EXP2(st[4 * g + 3]);
      rs0 += p0; rs1 += p1; rs2 += p2; rs3 += p3;
      pb[0] = (bf16)p0; pb[1] = (bf16)p1; pb[2] = (bf16)p2; pb[3] = (bf16)p3;
      u32x2 w2 = __builtin_bit_cast(u32x2, pb);
      q32[g][0] = w2[0];
      q32[g][1] = w2[1];
    }
#pragma unroll
    for (int t = 0; t < 2; ++t) {
      unsigned int a0 = q32[2 * t][0], a1 = q32[2 * t][1];
      unsigned int b0 = q32[2 * t + 1][0], b1 = q32[2 * t + 1][1];
      plswap(a0, b0);
      plswap(a1, b1);
      u32x4 f = {a0, a1, b0, b1};
      paw[hl * 2 + t] = __builtin_bit_cast(bf16x8, f);
    }
  };

  for (int kt = 0; kt < 32; ++kt) {
    if (kt == 31)
      wait_vm_barrier<0>();
    else
      wait_vm_barrier<4>();
    if (kt + 2 < 32) stage(kt + 2);
    const bf16* cK = sK[kt % 3];
    const bf16* cV = sV[kt % 3];

    // Preload V then K fragments (DS in-order: K-wait implies V done).
    bf16x8 vf[2][4], kf[2][4];
#pragma unroll
    for (int dh = 0; dh < 2; ++dh) {
      const int Rd = dh * 32 + lo5;
#pragma unroll
      for (int w = 0; w < 4; ++w)
        vf[dh][w] =
            *(const bf16x8*)(cV + Rd * 64 + (((2 * w + hi) ^ m7) << 3));
    }
#pragma unroll
    for (int hl = 0; hl < 2; ++hl) {
      const int R = hl * 32 + lo5;
#pragma unroll
      for (int i = 0; i < 4; ++i)
        kf[hl][i] =
            *(const bf16x8*)(cK + R * 64 + (((2 * i + hi) ^ m7) << 3));
    }

    // Both QK chains interleaved (independent accumulators).
    f32x16 st0 = (f32x16)(0.f), st1 = (f32x16)(0.f);
    __builtin_amdgcn_s_setprio(1);
#pragma unroll
    for (int i = 0; i < 4; ++i) {
      st0 = mfma32x16(kf[0][i], qf[i], st0);
      st1 = mfma32x16(kf[1][i], qf[i], st1);
    }
    __builtin_amdgcn_s_setprio(0);

    // softmax(hl0) -> paw[0..1]; PV w0,w1 runs while softmax(hl1) on VALU.
    softmax(st0, 0);
#pragma unroll
    for (int w = 0; w < 2; ++w) {
      oacc[0] = mfma32x16(paw[w], vf[0][w], oacc[0]);
      oacc[1] = mfma32x16(paw[w], vf[1][w], oacc[1]);
    }
    softmax(st1, 1);
    __builtin_amdgcn_s_setprio(1);
#pragma unroll
    for (int w = 2; w < 4; ++w) {
      oacc[0] = mfma32x16(paw[w], vf[0][w], oacc[0]);
      oacc[1] = mfma32x16(paw[w], vf[1][w], oacc[1]);
    }
    __builtin_amdgcn_s_setprio(0);
  }

  // combine row sums across hi halves; normalize; store
  float rsum = (rs0 + rs1) + (rs2 + rs3);
  rsum += __shfl_xor(rsum, 32, 64);
  const size_t obase = (size_t)(b * 2048 + q0) * 512 + h * 64;
#pragma unroll
  for (int r = 0; r < 16; ++r) {
    const int qloc = (r & 3) + 8 * (r >> 2) + 4 * hi;
    const float inv = 1.0f / __shfl(rsum, qloc, 64);
#pragma unroll
    for (int dh = 0; dh < 2; ++dh)
      O[obase + (size_t)qloc * 512 + dh * 32 + lo5] =
          (bf16)(oacc[dh][r] * inv);
  }
}

// ---------------- prep: convert x + all weight transposes ------------------
__global__ __launch_bounds__(256) void prep(
    const float* __restrict__ x, const float* __restrict__ Wq,
    const float* __restrict__ Wk, const float* __restrict__ Wv,
    const float* __restrict__ Wo, const float* __restrict__ W1,
    const float* __restrict__ W2, bf16* __restrict__ xb,
    bf16* __restrict__ WqkvT, bf16* __restrict__ WoT, bf16* __restrict__ W1T,
    bf16* __restrict__ W2T) {
  const int bid = blockIdx.x;
  if (bid < 4096) {
    const size_t i = ((size_t)bid * 256 + threadIdx.x) * 4;
    const float4 v = *(const float4*)(x + i);
    bf16x4 o;
    o[0] = (bf16)v.x; o[1] = (bf16)v.y; o[2] = (bf16)v.z; o[3] = (bf16)v.w;
    *(bf16x4*)(xb + i) = o;
    return;
  }
  const int t = bid - 4096;
  const float* in;
  bf16* out;
  int in_ld, out_ld, bx, by;
  if (t < 1024) {
    const int q = t >> 8, r = t & 255;
    bx = r & 15; by = r >> 4; in_ld = 512; out_ld = 512;
    in = (q == 0) ? Wq : (q == 1) ? Wk : (q == 2) ? Wv : Wo;
    out = (q == 0) ? WqkvT
          : (q == 1) ? WqkvT + 512 * 512
          : (q == 2) ? WqkvT + 2 * 512 * 512
                     : WoT;
  } else if (t < 2048) {
    const int r = t - 1024;
    bx = r & 63; by = r >> 6; in_ld = 2048; out_ld = 512;
    in = W1; out = W1T;
  } else {
    const int r = t - 2048;
    bx = r & 15; by = r >> 4; in_ld = 512; out_ld = 2048;
    in = W2; out = W2T;
  }
  __shared__ __align__(16) bf16 tl[32][33];
  const int tx = threadIdx.x & 31, ty = threadIdx.x >> 5;
  const int n0 = bx * 32, k0 = by * 32;
#pragma unroll
  for (int i = 0; i < 4; ++i)
    tl[ty + 8 * i][tx] = (bf16)in[(size_t)(k0 + ty + 8 * i) * in_ld + n0 + tx];
  __syncthreads();
#pragma unroll
  for (int i = 0; i < 4; ++i)
    out[(size_t)(n0 + ty + 8 * i) * out_ld + k0 + tx] = tl[tx][ty + 8 * i];
}

extern "C" void kernel_launch(void* const* d_in, const int* in_sizes, int n_in,
                              void* d_out, int out_size, void* d_ws,
                              size_t ws_size, hipStream_t stream) {
  const float* x = (const float*)d_in[0];
  const float* Wq = (const float*)d_in[1];
  const float* Wk = (const float*)d_in[2];
  const float* Wv = (const float*)d_in[3];
  const float* Wo = (const float*)d_in[4];
  const float* W1 = (const float*)d_in[5];
  const float* b1 = (const float*)d_in[6];
  const float* W2 = (const float*)d_in[7];
  const float* b2 = (const float*)d_in[8];
  float* out = (float*)d_out;  // fp32 output

  char* ws = (char*)d_ws;
  size_t off = 0;
  auto alloc = [&](size_t bytes) {
    char* p = ws + off;
    off += (bytes + 255) & ~(size_t)255;
    return p;
  };
  bf16* WqkvT = (bf16*)alloc(1536ULL * 512 * 2);
  bf16* WoT = (bf16*)alloc(512ULL * 512 * 2);
  bf16* W1T = (bf16*)alloc(2048ULL * 512 * 2);
  bf16* W2T = (bf16*)alloc(512ULL * 2048 * 2);
  bf16* xb = (bf16*)alloc(8192ULL * 512 * 2);      // bf16(x); reused as x2
  bf16* QKV = (bf16*)alloc(8192ULL * 1536 * 2);    // [8192][1536]
  bf16* Vt = (bf16*)alloc(32ULL * 64 * 2048 * 2);  // [B*H][64][2048]
  bf16* attn = (bf16*)alloc(8192ULL * 512 * 2);
  bf16* x2 = xb;     // xb dead after Wo gemm (residual source = xb, in place)
  bf16* hbuf = QKV;  // FFN hidden [8192][2048] = QKV+Vt region (dead by FFN1)

  const dim3 tb(256);
  prep<<<dim3(7168), tb, 0, stream>>>(x, Wq, Wk, Wv, Wo, W1, W2, xb, WqkvT,
                                      WoT, W1T, W2T);
  // QKV gemm: Q panel pre-scaled, V panel written transposed into Vt.
  gemm_bt<0, bf16, 128><<<dim3(12, 64), tb, 0, stream>>>(
      xb, WqkvT, QKV, nullptr, nullptr, Vt, 8192, 1536, 512);
  flash_attn<<<dim3(16, 32), tb, 0, stream>>>(QKV, Vt, attn);
  // Wo gemm: residual from xb (bf16, in-place with output x2 = xb).
  gemm_bt<1, bf16, 64><<<dim3(8, 64), tb, 0, stream>>>(
      attn, WoT, x2, nullptr, xb, nullptr, 8192, 512, 512);
  gemm256v2<<<dim3(8, 32), dim3(512), 0, stream>>>(x2, W1T, hbuf, b1, 8192,
                                                   2048, 512);
  gemm_bt<3, float, 64><<<dim3(8, 64), tb, 0, stream>>>(
      hbuf, W2T, out, b2, x2, nullptr, 8192, 512, 2048);
}